// Round 5
// baseline (75.970 us; speedup 1.0000x reference)
//
#include <hip/hip_runtime.h>
#include <math.h>

namespace {

constexpr int Bdim  = 4096;
constexpr int D_IN  = 2048;
constexpr int D_CTX = 512;
constexpr int UNITS = 2048;
constexpr int RANK  = 256;

typedef __bf16 bf16x8 __attribute__((ext_vector_type(8)));
typedef float  f32x4  __attribute__((ext_vector_type(4)));

// ---------------------------------------------------------------------------
// Prep: Ut[256][2048] = bf16(U^T), Wt[256][512] = bf16(W^T), Vb = bf16(V)
// grid (128, 3), 256 threads
// ---------------------------------------------------------------------------
__global__ __launch_bounds__(256) void k_prep(
    const float* __restrict__ U, const float* __restrict__ W,
    const float* __restrict__ V,
    __bf16* __restrict__ Ut, __bf16* __restrict__ Wt, __bf16* __restrict__ Vb) {
  const int job = blockIdx.y;
  const int t = threadIdx.x;
  if (job == 2) {  // straight convert V [2048*256]
    const size_t n = (size_t)UNITS * RANK;
    for (size_t i = ((size_t)blockIdx.x * 256 + t) * 4; i < n; i += (size_t)128 * 256 * 4) {
      float4 v = *(const float4*)(V + i);
      Vb[i + 0] = (__bf16)v.x; Vb[i + 1] = (__bf16)v.y;
      Vb[i + 2] = (__bf16)v.z; Vb[i + 3] = (__bf16)v.w;
    }
    return;
  }
  const float* src = job ? W : U;
  __bf16* dst      = job ? Wt : Ut;
  const int K = job ? D_CTX : D_IN;   // rows of src
  const int tilesK = K / 64;
  const int tid = blockIdx.x;
  if (tid >= tilesK * 4) return;      // N=256 -> 4 col tiles
  const int k0 = (tid % tilesK) * 64;
  const int n0 = (tid / tilesK) * 64;
  __shared__ __bf16 T[64][72];        // [n][k], pitch 144B (16B-aligned)
  const int i  = t >> 4;              // src row in tile (step 16)
  const int j4 = (t & 15) * 4;        // src col
  for (int ii = i; ii < 64; ii += 16) {
    float4 v = *(const float4*)(src + (size_t)(k0 + ii) * RANK + n0 + j4);
    T[j4 + 0][ii] = (__bf16)v.x;
    T[j4 + 1][ii] = (__bf16)v.y;
    T[j4 + 2][ii] = (__bf16)v.z;
    T[j4 + 3][ii] = (__bf16)v.w;
  }
  __syncthreads();
  const int jj = t >> 3;              // out row in tile (step 32)
  const int c  = t & 7;               // 16B chunk
  for (int j2 = jj; j2 < 64; j2 += 32) {
    bf16x8 v = *(const bf16x8*)&T[j2][c * 8];
    *(bf16x8*)(dst + (size_t)(n0 + j2) * K + k0 + c * 8) = v;
  }
}

// ---------------------------------------------------------------------------
// Templated bf16-MFMA GEMM, B transposed: C[M][N] = A[M][K] @ Bt[N][K]^T
//   mfma_f32_16x16x32_bf16. LDS tiles XOR-swizzled (byte ^= (row&7)<<4).
//   A_F32: stage A from fp32 global with in-register convert.
//   EPI 0: s    = bf16( S[n] * sigmoid(val + Bc[n]) )
//   EPI 1: proj = bf16( val * s[m,n] )
//   EPI 2: out  = f32 ( val + bias[n] )
// ---------------------------------------------------------------------------
template <int BM, int BN, int BK, int WAVES_M, int WAVES_N, bool A_F32, int EPI>
__global__ __launch_bounds__(256) void gemm_bt(
    const void* __restrict__ Ap, const __bf16* __restrict__ Bt,
    void* __restrict__ Cp, const float* __restrict__ e0,
    const float* __restrict__ e1, const __bf16* __restrict__ s_in,
    int Mt, int Nt, int Kt) {
  constexpr int FM = BM / WAVES_M / 16;
  constexpr int FN = BN / WAVES_N / 16;
  static_assert(WAVES_M * WAVES_N == 4, "4 waves");
  static_assert(BK == 64, "row = 128B");
  __shared__ __align__(16) __bf16 As[BM * BK];
  __shared__ __align__(16) __bf16 Bs[BN * BK];
  const int t  = threadIdx.x;
  const int bm = blockIdx.x * BM;
  const int bn = blockIdx.y * BN;
  const int w = t >> 6, l = t & 63;
  const int wr0 = (w / WAVES_N) * (FM * 16);
  const int wc0 = (w % WAVES_N) * (FN * 16);
  const int lrow = l & 15;
  const int lk   = l >> 4;
  f32x4 acc[FM][FN] = {};

  for (int k0 = 0; k0 < Kt; k0 += BK) {
    if (A_F32) {
      const float* A = (const float*)Ap;
#pragma unroll
      for (int c = t; c < BM * 8; c += 256) {
        const int row = c >> 3, kc = c & 7;
        const float* g = A + (size_t)(bm + row) * Kt + k0 + kc * 8;
        float4 lo = *(const float4*)g;
        float4 hi = *(const float4*)(g + 4);
        bf16x8 v;
        v[0] = (__bf16)lo.x; v[1] = (__bf16)lo.y; v[2] = (__bf16)lo.z; v[3] = (__bf16)lo.w;
        v[4] = (__bf16)hi.x; v[5] = (__bf16)hi.y; v[6] = (__bf16)hi.z; v[7] = (__bf16)hi.w;
        *(bf16x8*)((char*)As + row * 128 + ((kc ^ (row & 7)) * 16)) = v;
      }
    } else {
      const __bf16* A = (const __bf16*)Ap;
#pragma unroll
      for (int c = t; c < BM * 8; c += 256) {
        const int row = c >> 3, kc = c & 7;
        bf16x8 v = *(const bf16x8*)(A + (size_t)(bm + row) * Kt + k0 + kc * 8);
        *(bf16x8*)((char*)As + row * 128 + ((kc ^ (row & 7)) * 16)) = v;
      }
    }
#pragma unroll
    for (int c = t; c < BN * 8; c += 256) {
      const int row = c >> 3, kc = c & 7;
      bf16x8 v = *(const bf16x8*)(Bt + (size_t)(bn + row) * Kt + k0 + kc * 8);
      *(bf16x8*)((char*)Bs + row * 128 + ((kc ^ (row & 7)) * 16)) = v;
    }
    __syncthreads();
#pragma unroll
    for (int kk = 0; kk < BK / 32; ++kk) {
      bf16x8 af[FM], bfr[FN];
#pragma unroll
      for (int mf = 0; mf < FM; ++mf) {
        const int row = wr0 + mf * 16 + lrow;
        af[mf] = *(const bf16x8*)((const char*)As + row * 128 +
                                  (((kk * 4 + lk) ^ (row & 7)) * 16));
      }
#pragma unroll
      for (int nf = 0; nf < FN; ++nf) {
        const int row = wc0 + nf * 16 + lrow;
        bfr[nf] = *(const bf16x8*)((const char*)Bs + row * 128 +
                                   (((kk * 4 + lk) ^ (row & 7)) * 16));
      }
#pragma unroll
      for (int mf = 0; mf < FM; ++mf)
#pragma unroll
        for (int nf = 0; nf < FN; ++nf)
          acc[mf][nf] = __builtin_amdgcn_mfma_f32_16x16x32_bf16(
              af[mf], bfr[nf], acc[mf][nf], 0, 0, 0);
    }
    __syncthreads();
  }

#pragma unroll
  for (int mf = 0; mf < FM; ++mf) {
#pragma unroll
    for (int nf = 0; nf < FN; ++nf) {
#pragma unroll
      for (int r = 0; r < 4; ++r) {
        const int m = bm + wr0 + mf * 16 + lk * 4 + r;
        const int n = bn + wc0 + nf * 16 + lrow;
        const float val = acc[mf][nf][r];
        if (EPI == 0) {
          const float h  = val + e1[n];
          const float sg = 1.0f / (1.0f + __expf(-h));
          ((__bf16*)Cp)[(size_t)m * Nt + n] = (__bf16)(e0[n] * sg);
        } else if (EPI == 1) {
          const float sv = (float)s_in[(size_t)m * Nt + n];
          ((__bf16*)Cp)[(size_t)m * Nt + n] = (__bf16)(val * sv);
        } else {
          ((float*)Cp)[(size_t)m * Nt + n] = val + e0[n];
        }
      }
    }
  }
}

}  // namespace

extern "C" void kernel_launch(void* const* d_in, const int* in_sizes, int n_in,
                              void* d_out, int out_size, void* d_ws, size_t ws_size,
                              hipStream_t stream) {
  const float* inputs  = (const float*)d_in[0];  // [4096, 2048]
  const float* context = (const float*)d_in[1];  // [4096, 512]
  const float* U       = (const float*)d_in[2];  // [2048, 256]
  const float* S       = (const float*)d_in[3];  // [256]
  const float* V       = (const float*)d_in[4];  // [2048, 256]
  const float* W       = (const float*)d_in[5];  // [512, 256]
  const float* Bc      = (const float*)d_in[6];  // [256]
  const float* bias    = (const float*)d_in[7];  // [2048]
  float* out = (float*)d_out;                    // [4096, 2048]

  char* ws = (char*)d_ws;
  __bf16* Ut   = (__bf16*)(ws);                  // 256x2048  (1 MB)
  __bf16* Wt   = (__bf16*)(ws + 1048576);        // 256x512   (256 KB)
  __bf16* Vb   = (__bf16*)(ws + 1310720);        // 2048x256  (1 MB)
  __bf16* sbuf = (__bf16*)(ws + 2359296);        // 4096x256  (2 MB)
  __bf16* proj = (__bf16*)(ws + 4456448);        // 4096x256  (2 MB)

  // 1) weight transpose+convert (Ut, Wt) and V convert (Vb)
  k_prep<<<dim3(128, 3), 256, 0, stream>>>(U, W, V, Ut, Wt, Vb);

  // 2) s = bf16( S * sigmoid(ctx @ W + Bc) )   [4096 x 256], K=512, 512 blocks
  gemm_bt<32, 64, 64, 2, 2, true, 0><<<dim3(Bdim / 32, RANK / 64), 256, 0, stream>>>(
      context, Wt, sbuf, S, Bc, nullptr, Bdim, RANK, D_CTX);

  // 3) proj = bf16( (x @ U) * s )              [4096 x 256], K=2048, 512 blocks
  //    x read exactly once from HBM; Ut/x-re-reads served by L2/L3.
  gemm_bt<32, 64, 64, 2, 2, true, 1><<<dim3(Bdim / 32, RANK / 64), 256, 0, stream>>>(
      inputs, Ut, proj, nullptr, nullptr, sbuf, Bdim, RANK, D_IN);

  // 4) out = proj @ V^T + bias                 [4096 x 2048], K=256, 512 blocks
  gemm_bt<128, 128, 64, 2, 2, false, 2><<<dim3(Bdim / 128, UNITS / 128), 256, 0, stream>>>(
      proj, Vb, out, bias, nullptr, nullptr, Bdim, UNITS, RANK);
}

// Round 6
// 49.733 us; speedup vs baseline: 1.5275x; 1.5275x over previous
//
#include <hip/hip_runtime.h>
#include <math.h>

namespace {

constexpr int Bdim  = 4096;
constexpr int D_IN  = 2048;
constexpr int D_CTX = 512;
constexpr int UNITS = 2048;
constexpr int RANK  = 256;
constexpr int SPLIT = 8;

typedef __bf16 bf16x8 __attribute__((ext_vector_type(8)));
typedef float  f32x4  __attribute__((ext_vector_type(4)));

// ---------------------------------------------------------------------------
// Prep: Ut[256][2048] = bf16(U^T), Wt[256][512] = bf16(W^T)
// ---------------------------------------------------------------------------
__global__ __launch_bounds__(256) void k_prep(
    const float* __restrict__ U, const float* __restrict__ W,
    __bf16* __restrict__ Ut, __bf16* __restrict__ Wt) {
  const int job = blockIdx.y;
  const int t = threadIdx.x;
  const float* src = job ? W : U;
  __bf16* dst      = job ? Wt : Ut;
  const int K = job ? D_CTX : D_IN;   // rows of src
  const int tilesK = K / 64;
  const int tid = blockIdx.x;
  if (tid >= tilesK * 4) return;      // N=256 -> 4 col tiles
  const int k0 = (tid % tilesK) * 64;
  const int n0 = (tid / tilesK) * 64;
  __shared__ __bf16 T[64][72];        // [n][k], pitch 144B (16B-aligned)
  const int i  = t >> 4;              // src row in tile (step 16)
  const int j4 = (t & 15) * 4;        // src col
  for (int ii = i; ii < 64; ii += 16) {
    float4 v = *(const float4*)(src + (size_t)(k0 + ii) * RANK + n0 + j4);
    T[j4 + 0][ii] = (__bf16)v.x;
    T[j4 + 1][ii] = (__bf16)v.y;
    T[j4 + 2][ii] = (__bf16)v.z;
    T[j4 + 3][ii] = (__bf16)v.w;
  }
  __syncthreads();
  const int jj = t >> 3;              // out row in tile (step 32)
  const int c  = t & 7;               // 16B chunk
  for (int j2 = jj; j2 < 64; j2 += 32) {
    bf16x8 v = *(const bf16x8*)&T[j2][c * 8];
    *(bf16x8*)(dst + (size_t)(n0 + j2) * K + k0 + c * 8) = v;
  }
}

// ---------------------------------------------------------------------------
// Templated bf16-MFMA GEMM, B transposed: C[M][N] = A[M][K] @ Bt[N][K]^T
//   mfma_f32_16x16x32_bf16. LDS XOR-swizzled (byte ^= (row&7)<<4).
//   Register-prefetch staging: issue tile k+1 global loads before MFMA of k
//   (T14 issue-early/write-late), single LDS buffer, 2 barriers/iter.
//   A_F32 / B_F32: operand staged from fp32 global, converted at ds_write.
//   EPI 2: out  = f32( val + bias[n] )
//   EPI 3: split-K partial: blockIdx.y = K-slice; bf16 partial at slice
//   EPI 4: gate+reduce: proj = bf16( (sum_sl part) * S[n]*sigmoid(val+Bc[n]) )
// ---------------------------------------------------------------------------
template <int BM, int BN, int BK, int WAVES_M, int WAVES_N,
          bool A_F32, bool B_F32, int EPI>
__global__ __launch_bounds__(256) void gemm_bt(
    const void* __restrict__ Ap, const void* __restrict__ Btp,
    void* __restrict__ Cp, const float* __restrict__ e0,
    const float* __restrict__ e1, const __bf16* __restrict__ part_in,
    int Mt, int Nt, int Kt, int kchunk) {
  constexpr int FM = BM / WAVES_M / 16;
  constexpr int FN = BN / WAVES_N / 16;
  constexpr int ACH = BM * 8 / 256;   // staging chunks per thread (A)
  constexpr int BCH = BN * 8 / 256;   // staging chunks per thread (B)
  static_assert(WAVES_M * WAVES_N == 4, "4 waves");
  static_assert(BK == 64, "row = 128B");
  static_assert(ACH >= 1 && BCH >= 1, "chunking");
  static_assert(EPI != 4 || (BM * BN * 4 <= BN * BK * 2), "red fits in Bs");
  __shared__ __align__(16) __bf16 As[BM * BK];
  __shared__ __align__(16) __bf16 Bs[BN * BK];
  const int t  = threadIdx.x;
  const int bm = blockIdx.x * BM;
  const int bn = (EPI == 3) ? 0 : blockIdx.y * BN;
  const int k_lo = (EPI == 3) ? blockIdx.y * kchunk : 0;
  const int k_hi = (EPI == 3) ? k_lo + kchunk : Kt;
  const int w = t >> 6, l = t & 63;
  const int wr0 = (w / WAVES_N) * (FM * 16);
  const int wc0 = (w % WAVES_N) * (FN * 16);
  const int lrow = l & 15;
  const int lk   = l >> 4;
  f32x4 acc[FM][FN] = {};

  // register staging buffers (prefetch holds raw loads until ds_write)
  float4 a_lo[ACH], a_hi[ACH];
  bf16x8 a_bf[ACH];
  float4 b_lo[BCH], b_hi[BCH];
  bf16x8 b_bf[BCH];

  auto LOADA = [&](int k0) {
#pragma unroll
    for (int ci = 0; ci < ACH; ++ci) {
      const int c = t + ci * 256;
      const int row = c >> 3, kc = c & 7;
      if constexpr (A_F32) {
        const float* g = (const float*)Ap + (size_t)(bm + row) * Kt + k0 + kc * 8;
        a_lo[ci] = *(const float4*)g;
        a_hi[ci] = *(const float4*)(g + 4);
      } else {
        a_bf[ci] = *(const bf16x8*)((const __bf16*)Ap +
                                    (size_t)(bm + row) * Kt + k0 + kc * 8);
      }
    }
  };
  auto LOADB = [&](int k0) {
#pragma unroll
    for (int ci = 0; ci < BCH; ++ci) {
      const int c = t + ci * 256;
      const int row = c >> 3, kc = c & 7;
      if constexpr (B_F32) {
        const float* g = (const float*)Btp + (size_t)(bn + row) * Kt + k0 + kc * 8;
        b_lo[ci] = *(const float4*)g;
        b_hi[ci] = *(const float4*)(g + 4);
      } else {
        b_bf[ci] = *(const bf16x8*)((const __bf16*)Btp +
                                    (size_t)(bn + row) * Kt + k0 + kc * 8);
      }
    }
  };
  auto WRITEA = [&]() {
#pragma unroll
    for (int ci = 0; ci < ACH; ++ci) {
      const int c = t + ci * 256;
      const int row = c >> 3, kc = c & 7;
      bf16x8 v;
      if constexpr (A_F32) {
        v[0] = (__bf16)a_lo[ci].x; v[1] = (__bf16)a_lo[ci].y;
        v[2] = (__bf16)a_lo[ci].z; v[3] = (__bf16)a_lo[ci].w;
        v[4] = (__bf16)a_hi[ci].x; v[5] = (__bf16)a_hi[ci].y;
        v[6] = (__bf16)a_hi[ci].z; v[7] = (__bf16)a_hi[ci].w;
      } else {
        v = a_bf[ci];
      }
      *(bf16x8*)((char*)As + row * 128 + ((kc ^ (row & 7)) * 16)) = v;
    }
  };
  auto WRITEB = [&]() {
#pragma unroll
    for (int ci = 0; ci < BCH; ++ci) {
      const int c = t + ci * 256;
      const int row = c >> 3, kc = c & 7;
      bf16x8 v;
      if constexpr (B_F32) {
        v[0] = (__bf16)b_lo[ci].x; v[1] = (__bf16)b_lo[ci].y;
        v[2] = (__bf16)b_lo[ci].z; v[3] = (__bf16)b_lo[ci].w;
        v[4] = (__bf16)b_hi[ci].x; v[5] = (__bf16)b_hi[ci].y;
        v[6] = (__bf16)b_hi[ci].z; v[7] = (__bf16)b_hi[ci].w;
      } else {
        v = b_bf[ci];
      }
      *(bf16x8*)((char*)Bs + row * 128 + ((kc ^ (row & 7)) * 16)) = v;
    }
  };

  LOADA(k_lo);
  LOADB(k_lo);
  for (int k0 = k_lo; k0 < k_hi; k0 += BK) {
    WRITEA();          // waits vmcnt on the in-flight loads
    WRITEB();
    __syncthreads();
    if (k0 + BK < k_hi) {  // prefetch next tile; latency hides under MFMA
      LOADA(k0 + BK);
      LOADB(k0 + BK);
    }
#pragma unroll
    for (int kk = 0; kk < BK / 32; ++kk) {
      bf16x8 af[FM], bfr[FN];
#pragma unroll
      for (int mf = 0; mf < FM; ++mf) {
        const int row = wr0 + mf * 16 + lrow;
        af[mf] = *(const bf16x8*)((const char*)As + row * 128 +
                                  (((kk * 4 + lk) ^ (row & 7)) * 16));
      }
#pragma unroll
      for (int nf = 0; nf < FN; ++nf) {
        const int row = wc0 + nf * 16 + lrow;
        bfr[nf] = *(const bf16x8*)((const char*)Bs + row * 128 +
                                   (((kk * 4 + lk) ^ (row & 7)) * 16));
      }
#pragma unroll
      for (int mf = 0; mf < FM; ++mf)
#pragma unroll
        for (int nf = 0; nf < FN; ++nf)
          acc[mf][nf] = __builtin_amdgcn_mfma_f32_16x16x32_bf16(
              af[mf], bfr[nf], acc[mf][nf], 0, 0, 0);
    }
    __syncthreads();
  }

  float* red = (float*)Bs;  // EPI==4: reuse Bs as f32 [BM][BN] reduce buffer
  if (EPI == 4) {
    // Cooperative, fully-coalesced reduce of bf16 partials into LDS.
    const int row = t >> 3;            // 0..31 (BM=32)
    const int ch  = (t & 7) * 8;       // 0..56 (BN=64, 8 bf16 per thread)
    float racc[8] = {};
    for (int sl = 0; sl < kchunk; ++sl) {
      bf16x8 v = *(const bf16x8*)(part_in +
                    ((size_t)sl * Mt + bm + row) * Nt + bn + ch);
#pragma unroll
      for (int i = 0; i < 8; ++i) racc[i] += (float)v[i];
    }
#pragma unroll
    for (int i = 0; i < 8; ++i) red[row * BN + ch + i] = racc[i];
    __syncthreads();
  }

#pragma unroll
  for (int mf = 0; mf < FM; ++mf) {
#pragma unroll
    for (int nf = 0; nf < FN; ++nf) {
#pragma unroll
      for (int r = 0; r < 4; ++r) {
        const int lm = wr0 + mf * 16 + lk * 4 + r;
        const int ln = wc0 + nf * 16 + lrow;
        const int m = bm + lm;
        const int n = bn + ln;
        const float val = acc[mf][nf][r];
        if (EPI == 2) {
          ((float*)Cp)[(size_t)m * Nt + n] = val + e0[n];
        } else if (EPI == 3) {
          ((__bf16*)Cp)[(size_t)blockIdx.y * Mt * Nt + (size_t)m * Nt + n] =
              (__bf16)val;
        } else {  // EPI == 4
          const float h    = val + e1[n];
          const float sval = e0[n] / (1.0f + __expf(-h));
          ((__bf16*)Cp)[(size_t)m * Nt + n] = (__bf16)(red[lm * BN + ln] * sval);
        }
      }
    }
  }
}

}  // namespace

extern "C" void kernel_launch(void* const* d_in, const int* in_sizes, int n_in,
                              void* d_out, int out_size, void* d_ws, size_t ws_size,
                              hipStream_t stream) {
  const float* inputs  = (const float*)d_in[0];  // [4096, 2048]
  const float* context = (const float*)d_in[1];  // [4096, 512]
  const float* U       = (const float*)d_in[2];  // [2048, 256]
  const float* S       = (const float*)d_in[3];  // [256]
  const float* V       = (const float*)d_in[4];  // [2048, 256]
  const float* W       = (const float*)d_in[5];  // [512, 256]
  const float* Bc      = (const float*)d_in[6];  // [256]
  const float* bias    = (const float*)d_in[7];  // [2048]
  float* out = (float*)d_out;                    // [4096, 2048]

  char* ws = (char*)d_ws;
  __bf16* Ut   = (__bf16*)(ws);                  // 256x2048         (1 MB)
  __bf16* Wt   = (__bf16*)(ws + 1048576);        // 256x512          (256 KB)
  __bf16* proj = (__bf16*)(ws + 1310720);        // 4096x256         (2 MB)
  __bf16* part = (__bf16*)(ws + 3407872);        // SPLIT x4096x256  (16 MB)

  // 1) weight transpose+convert (Ut, Wt)
  k_prep<<<dim3(128, 2), 256, 0, stream>>>(U, W, Ut, Wt);

  // 2) xU bf16 partials: [8][4096][256], K-chunk = 256
  gemm_bt<32, 256, 64, 1, 4, true, false, 3>
      <<<dim3(Bdim / 32, SPLIT), 256, 0, stream>>>(
      inputs, Ut, part, nullptr, nullptr, nullptr, Bdim, RANK, D_IN, D_IN / SPLIT);

  // 3) gate GEMM + fused partial-reduce:
  //    proj = bf16( (sum partials) * S*sigmoid(ctx@W + Bc) )
  gemm_bt<32, 64, 64, 2, 2, true, false, 4>
      <<<dim3(Bdim / 32, RANK / 64), 256, 0, stream>>>(
      context, Wt, proj, S, Bc, part, Bdim, RANK, D_CTX, SPLIT);

  // 4) out = proj @ V^T + bias   (V staged directly from fp32)
  gemm_bt<128, 128, 64, 2, 2, false, true, 2>
      <<<dim3(Bdim / 128, UNITS / 128), 256, 0, stream>>>(
      proj, V, out, bias, nullptr, nullptr, Bdim, UNITS, RANK, 0);
}

// Round 7
// 48.995 us; speedup vs baseline: 1.5506x; 1.0151x over previous
//
#include <hip/hip_runtime.h>
#include <math.h>

namespace {

constexpr int Bdim  = 4096;
constexpr int D_IN  = 2048;
constexpr int D_CTX = 512;
constexpr int UNITS = 2048;
constexpr int RANK  = 256;
constexpr int SPLIT = 8;

typedef __bf16 bf16x8 __attribute__((ext_vector_type(8)));
typedef float  f32x4  __attribute__((ext_vector_type(4)));

// ---------------------------------------------------------------------------
// Prep: Ut[256][2048] = bf16(U^T), Wt[256][512] = bf16(W^T)
// ---------------------------------------------------------------------------
__global__ __launch_bounds__(256) void k_prep(
    const float* __restrict__ U, const float* __restrict__ W,
    __bf16* __restrict__ Ut, __bf16* __restrict__ Wt) {
  const int job = blockIdx.y;
  const int t = threadIdx.x;
  const float* src = job ? W : U;
  __bf16* dst      = job ? Wt : Ut;
  const int K = job ? D_CTX : D_IN;   // rows of src
  const int tilesK = K / 64;
  const int tid = blockIdx.x;
  if (tid >= tilesK * 4) return;      // N=256 -> 4 col tiles
  const int k0 = (tid % tilesK) * 64;
  const int n0 = (tid / tilesK) * 64;
  __shared__ __bf16 T[64][72];        // [n][k], pitch 144B (16B-aligned)
  const int i  = t >> 4;              // src row in tile (step 16)
  const int j4 = (t & 15) * 4;        // src col
  for (int ii = i; ii < 64; ii += 16) {
    float4 v = *(const float4*)(src + (size_t)(k0 + ii) * RANK + n0 + j4);
    T[j4 + 0][ii] = (__bf16)v.x;
    T[j4 + 1][ii] = (__bf16)v.y;
    T[j4 + 2][ii] = (__bf16)v.z;
    T[j4 + 3][ii] = (__bf16)v.w;
  }
  __syncthreads();
  const int jj = t >> 3;              // out row in tile (step 32)
  const int c  = t & 7;               // 16B chunk
  for (int j2 = jj; j2 < 64; j2 += 32) {
    bf16x8 v = *(const bf16x8*)&T[j2][c * 8];
    *(bf16x8*)(dst + (size_t)(n0 + j2) * K + k0 + c * 8) = v;
  }
}

// ---------------------------------------------------------------------------
// Merged gate + split-K partial kernel.  BM=32, BN=256, BK=64, 4 waves (1x4).
//   blockIdx.y == 0      : s = bf16( S*sigmoid(ctx @ Wt^T + Bc) )   K=512
//   blockIdx.y == 1+sl   : part[sl] = bf16( x @ Ut^T )  K-chunk = 256
// Register-prefetch staging, LDS XOR-swizzled (byte ^= (row&7)<<4).
// ---------------------------------------------------------------------------
__global__ __launch_bounds__(256) void k_pg(
    const float* __restrict__ x,   const __bf16* __restrict__ Ut,
    const float* __restrict__ ctx, const __bf16* __restrict__ Wt,
    const float* __restrict__ S,   const float* __restrict__ Bc,
    __bf16* __restrict__ part, __bf16* __restrict__ s_out) {
  constexpr int BM = 32, BN = 256, BK = 64;
  __shared__ __align__(16) __bf16 As[BM * BK];
  __shared__ __align__(16) __bf16 Bs[BN * BK];
  const int t = threadIdx.x;
  const bool gate = (blockIdx.y == 0);
  const int slice = (int)blockIdx.y - 1;
  const int bm = blockIdx.x * BM;
  const float*  A = gate ? ctx : x;
  const __bf16* B = gate ? Wt  : Ut;
  const int Kt   = gate ? D_CTX : D_IN;
  const int k_lo = gate ? 0 : slice * (D_IN / SPLIT);
  const int k_hi = gate ? D_CTX : k_lo + (D_IN / SPLIT);
  const int w = t >> 6, l = t & 63;
  const int wc0 = w * 64;             // wave's N offset (1x4)
  const int lrow = l & 15;
  const int lk   = l >> 4;
  f32x4 acc[2][4] = {};

  float4 a_lo, a_hi;
  bf16x8 b_bf[8];
  const int srow = t >> 3, skc = t & 7;   // A staging coords (1 chunk/thread)

  auto LOADA = [&](int k0) {
    const float* g = A + (size_t)(bm + srow) * Kt + k0 + skc * 8;
    a_lo = *(const float4*)g;
    a_hi = *(const float4*)(g + 4);
  };
  auto LOADB = [&](int k0) {
#pragma unroll
    for (int ci = 0; ci < 8; ++ci) {
      const int c = t + ci * 256;
      const int row = c >> 3, kc = c & 7;
      b_bf[ci] = *(const bf16x8*)(B + (size_t)row * Kt + k0 + kc * 8);
    }
  };
  auto WRITEA = [&]() {
    bf16x8 v;
    v[0] = (__bf16)a_lo.x; v[1] = (__bf16)a_lo.y;
    v[2] = (__bf16)a_lo.z; v[3] = (__bf16)a_lo.w;
    v[4] = (__bf16)a_hi.x; v[5] = (__bf16)a_hi.y;
    v[6] = (__bf16)a_hi.z; v[7] = (__bf16)a_hi.w;
    *(bf16x8*)((char*)As + srow * 128 + ((skc ^ (srow & 7)) * 16)) = v;
  };
  auto WRITEB = [&]() {
#pragma unroll
    for (int ci = 0; ci < 8; ++ci) {
      const int c = t + ci * 256;
      const int row = c >> 3, kc = c & 7;
      *(bf16x8*)((char*)Bs + row * 128 + ((kc ^ (row & 7)) * 16)) = b_bf[ci];
    }
  };

  LOADA(k_lo);
  LOADB(k_lo);
  for (int k0 = k_lo; k0 < k_hi; k0 += BK) {
    WRITEA();
    WRITEB();
    __syncthreads();
    if (k0 + BK < k_hi) {  // prefetch next tile; latency hides under MFMA
      LOADA(k0 + BK);
      LOADB(k0 + BK);
    }
#pragma unroll
    for (int kk = 0; kk < 2; ++kk) {
      bf16x8 af[2], bfr[4];
#pragma unroll
      for (int mf = 0; mf < 2; ++mf) {
        const int row = mf * 16 + lrow;
        af[mf] = *(const bf16x8*)((const char*)As + row * 128 +
                                  (((kk * 4 + lk) ^ (row & 7)) * 16));
      }
#pragma unroll
      for (int nf = 0; nf < 4; ++nf) {
        const int row = wc0 + nf * 16 + lrow;
        bfr[nf] = *(const bf16x8*)((const char*)Bs + row * 128 +
                                   (((kk * 4 + lk) ^ (row & 7)) * 16));
      }
#pragma unroll
      for (int mf = 0; mf < 2; ++mf)
#pragma unroll
        for (int nf = 0; nf < 4; ++nf)
          acc[mf][nf] = __builtin_amdgcn_mfma_f32_16x16x32_bf16(
              af[mf], bfr[nf], acc[mf][nf], 0, 0, 0);
    }
    __syncthreads();
  }

#pragma unroll
  for (int mf = 0; mf < 2; ++mf) {
#pragma unroll
    for (int nf = 0; nf < 4; ++nf) {
#pragma unroll
      for (int r = 0; r < 4; ++r) {
        const int m = bm + mf * 16 + lk * 4 + r;
        const int n = wc0 + nf * 16 + lrow;
        const float val = acc[mf][nf][r];
        if (gate) {
          const float h = val + Bc[n];
          s_out[(size_t)m * RANK + n] = (__bf16)(S[n] / (1.0f + __expf(-h)));
        } else {
          part[((size_t)slice * Bdim + m) * RANK + n] = (__bf16)val;
        }
      }
    }
  }
}

// ---------------------------------------------------------------------------
// Combine: proj = bf16( (sum_sl part[sl]) * s ), 8 elems/thread, 512 blocks
// ---------------------------------------------------------------------------
__global__ __launch_bounds__(256) void k_combine(
    const __bf16* __restrict__ part, const __bf16* __restrict__ s,
    __bf16* __restrict__ proj) {
  const size_t i8 = ((size_t)blockIdx.x * 256 + threadIdx.x) * 8;
  float sum[8] = {};
#pragma unroll
  for (int sl = 0; sl < SPLIT; ++sl) {
    bf16x8 v = *(const bf16x8*)(part + (size_t)sl * Bdim * RANK + i8);
#pragma unroll
    for (int i = 0; i < 8; ++i) sum[i] += (float)v[i];
  }
  bf16x8 sv = *(const bf16x8*)(s + i8);
  bf16x8 o;
#pragma unroll
  for (int i = 0; i < 8; ++i) o[i] = (__bf16)(sum[i] * (float)sv[i]);
  *(bf16x8*)(proj + i8) = o;
}

// ---------------------------------------------------------------------------
// Out: out[m][n] = proj[m][:] @ V[n][:] + bias[n].  BM=BN=128, 4 waves (2x2).
//   A = proj bf16 [4096][256]; B = V fp32 [2048][256] staged w/ convert.
//   XCD-aware bijective swizzle of the 512 tiles (64 consecutive per XCD).
// ---------------------------------------------------------------------------
__global__ __launch_bounds__(256) void k_out(
    const __bf16* __restrict__ proj, const float* __restrict__ V,
    const float* __restrict__ bias, float* __restrict__ out) {
  constexpr int BM = 128, BN = 128, BK = 64;
  constexpr int Kt = RANK;
  __shared__ __align__(16) __bf16 As[BM * BK];
  __shared__ __align__(16) __bf16 Bs[BN * BK];
  const int t = threadIdx.x;
  // swizzle: lin -> (lin%8)*64 + lin/8 ; grid (32,16) = 512 tiles, 64/XCD
  const int lin = (int)(blockIdx.y * gridDim.x + blockIdx.x);
  const int swz = (lin & 7) * 64 + (lin >> 3);
  const int bm = (swz & 31) * BM;   // 32 m-tiles
  const int bn = (swz >> 5) * BN;   // 16 n-tiles
  const int w = t >> 6, l = t & 63;
  const int wr0 = (w >> 1) * 64;    // 2x2 waves
  const int wc0 = (w & 1) * 64;
  const int lrow = l & 15;
  const int lk   = l >> 4;
  f32x4 acc[4][4] = {};

  bf16x8 a_bf[4];
  float4 b_lo[4], b_hi[4];

  auto LOADA = [&](int k0) {
#pragma unroll
    for (int ci = 0; ci < 4; ++ci) {
      const int c = t + ci * 256;
      const int row = c >> 3, kc = c & 7;
      a_bf[ci] = *(const bf16x8*)(proj + (size_t)(bm + row) * Kt + k0 + kc * 8);
    }
  };
  auto LOADB = [&](int k0) {
#pragma unroll
    for (int ci = 0; ci < 4; ++ci) {
      const int c = t + ci * 256;
      const int row = c >> 3, kc = c & 7;
      const float* g = V + (size_t)(bn + row) * Kt + k0 + kc * 8;
      b_lo[ci] = *(const float4*)g;
      b_hi[ci] = *(const float4*)(g + 4);
    }
  };
  auto WRITEA = [&]() {
#pragma unroll
    for (int ci = 0; ci < 4; ++ci) {
      const int c = t + ci * 256;
      const int row = c >> 3, kc = c & 7;
      *(bf16x8*)((char*)As + row * 128 + ((kc ^ (row & 7)) * 16)) = a_bf[ci];
    }
  };
  auto WRITEB = [&]() {
#pragma unroll
    for (int ci = 0; ci < 4; ++ci) {
      const int c = t + ci * 256;
      const int row = c >> 3, kc = c & 7;
      bf16x8 v;
      v[0] = (__bf16)b_lo[ci].x; v[1] = (__bf16)b_lo[ci].y;
      v[2] = (__bf16)b_lo[ci].z; v[3] = (__bf16)b_lo[ci].w;
      v[4] = (__bf16)b_hi[ci].x; v[5] = (__bf16)b_hi[ci].y;
      v[6] = (__bf16)b_hi[ci].z; v[7] = (__bf16)b_hi[ci].w;
      *(bf16x8*)((char*)Bs + row * 128 + ((kc ^ (row & 7)) * 16)) = v;
    }
  };

  LOADA(0);
  LOADB(0);
  for (int k0 = 0; k0 < Kt; k0 += BK) {
    WRITEA();
    WRITEB();
    __syncthreads();
    if (k0 + BK < Kt) {
      LOADA(k0 + BK);
      LOADB(k0 + BK);
    }
#pragma unroll
    for (int kk = 0; kk < 2; ++kk) {
      bf16x8 af[4], bfr[4];
#pragma unroll
      for (int mf = 0; mf < 4; ++mf) {
        const int row = wr0 + mf * 16 + lrow;
        af[mf] = *(const bf16x8*)((const char*)As + row * 128 +
                                  (((kk * 4 + lk) ^ (row & 7)) * 16));
      }
#pragma unroll
      for (int nf = 0; nf < 4; ++nf) {
        const int row = wc0 + nf * 16 + lrow;
        bfr[nf] = *(const bf16x8*)((const char*)Bs + row * 128 +
                                   (((kk * 4 + lk) ^ (row & 7)) * 16));
      }
#pragma unroll
      for (int mf = 0; mf < 4; ++mf)
#pragma unroll
        for (int nf = 0; nf < 4; ++nf)
          acc[mf][nf] = __builtin_amdgcn_mfma_f32_16x16x32_bf16(
              af[mf], bfr[nf], acc[mf][nf], 0, 0, 0);
    }
    __syncthreads();
  }

#pragma unroll
  for (int mf = 0; mf < 4; ++mf) {
#pragma unroll
    for (int nf = 0; nf < 4; ++nf) {
#pragma unroll
      for (int r = 0; r < 4; ++r) {
        const int m = bm + wr0 + mf * 16 + lk * 4 + r;
        const int n = bn + wc0 + nf * 16 + lrow;
        out[(size_t)m * UNITS + n] = acc[mf][nf][r] + bias[n];
      }
    }
  }
}

}  // namespace

extern "C" void kernel_launch(void* const* d_in, const int* in_sizes, int n_in,
                              void* d_out, int out_size, void* d_ws, size_t ws_size,
                              hipStream_t stream) {
  const float* inputs  = (const float*)d_in[0];  // [4096, 2048]
  const float* context = (const float*)d_in[1];  // [4096, 512]
  const float* U       = (const float*)d_in[2];  // [2048, 256]
  const float* S       = (const float*)d_in[3];  // [256]
  const float* V       = (const float*)d_in[4];  // [2048, 256]
  const float* W       = (const float*)d_in[5];  // [512, 256]
  const float* Bc      = (const float*)d_in[6];  // [256]
  const float* bias    = (const float*)d_in[7];  // [2048]
  float* out = (float*)d_out;                    // [4096, 2048]

  char* ws = (char*)d_ws;
  __bf16* Ut   = (__bf16*)(ws);                  // 256x2048         (1 MB)
  __bf16* Wt   = (__bf16*)(ws + 1048576);        // 256x512          (256 KB)
  __bf16* proj = (__bf16*)(ws + 1310720);        // 4096x256         (2 MB)
  __bf16* sbuf = (__bf16*)(ws + 3407872);        // 4096x256         (2 MB)
  __bf16* part = (__bf16*)(ws + 5505024);        // SPLIT x4096x256  (16 MB)

  // 1) weight transpose+convert (Ut, Wt)
  k_prep<<<dim3(128, 2), 256, 0, stream>>>(U, W, Ut, Wt);

  // 2) merged: gate (y=0, writes s) + xU split-K partials (y=1..8)
  k_pg<<<dim3(Bdim / 32, SPLIT + 1), 256, 0, stream>>>(
      inputs, Ut, context, Wt, S, Bc, part, sbuf);

  // 3) proj = bf16( (sum partials) * s )   — pure-BW elementwise
  k_combine<<<dim3((Bdim * RANK) / (256 * 8)), 256, 0, stream>>>(part, sbuf, proj);

  // 4) out = proj @ V^T + bias   (V staged from fp32, XCD-swizzled tiles)
  k_out<<<dim3(Bdim / 128, UNITS / 128), 256, 0, stream>>>(proj, V, bias, out);
}